// Round 1
// baseline (5925.142 us; speedup 1.0000x reference)
//
#include <hip/hip_runtime.h>

#define HD 1024
#define ID 1024
#define BATCH 64
#define SEQ 512
#define BS (BATCH*SEQ)     // 32768 rows
#define CHUNK 64
#define NCHUNK (SEQ/CHUNK) // 8
#define LR_OVER_I (0.01f/1024.0f)

// ---------- prep: Wd = W_init - Wt ; bd = b_init - bt ----------
__global__ void prep_kernel(const float* __restrict__ Wi, const float* __restrict__ Wt,
                            const float* __restrict__ bi, const float* __restrict__ bt,
                            float* __restrict__ Wd, float* __restrict__ bd)
{
    int idx = blockIdx.x * 256 + threadIdx.x;
    if (idx < HD * ID) Wd[idx] = Wi[idx] - Wt[idx];
    if (idx < ID)      bd[idx] = bi[idx] - bt[idx];
}

// ---------- generic fp32 GEMM: C = alpha*(A@B) + beta*C + bias ----------
// 64x64 tile, BK=16, 256 threads, 4x4 micro-tile. Dims must be multiples of 64/16.
__global__ __launch_bounds__(256) void gemm_f32(
    const float* __restrict__ A, long sAb, int lda,
    const float* __restrict__ B, long sBb, int ldb,
    float* __restrict__ C, long sCb, int ldc,
    int K, const float* __restrict__ bias, float alpha, float beta)
{
    A += (long)blockIdx.z * sAb;
    B += (long)blockIdx.z * sBb;
    C += (long)blockIdx.z * sCb;
    const int tn = blockIdx.x * 64;
    const int tm = blockIdx.y * 64;
    __shared__ float As[16][64];
    __shared__ float Bsh[16][64];
    const int tid = threadIdx.x;
    const int tx = tid & 15, ty = tid >> 4;
    const int am = tid >> 2, ak4 = (tid & 3) << 2;
    const int bk = tid >> 4, bn4 = (tid & 15) << 2;
    float acc[4][4] = {};
    for (int k0 = 0; k0 < K; k0 += 16) {
        float4 av = *(const float4*)(A + (long)(tm + am) * lda + (k0 + ak4));
        float4 bv = *(const float4*)(B + (long)(k0 + bk) * ldb + (tn + bn4));
        __syncthreads();
        As[ak4 + 0][am] = av.x; As[ak4 + 1][am] = av.y;
        As[ak4 + 2][am] = av.z; As[ak4 + 3][am] = av.w;
        *(float4*)&Bsh[bk][bn4] = bv;
        __syncthreads();
#pragma unroll
        for (int k = 0; k < 16; ++k) {
            float4 a = *(const float4*)&As[k][ty << 2];
            float4 b = *(const float4*)&Bsh[k][tx << 2];
            float ar[4] = {a.x, a.y, a.z, a.w};
            float br[4] = {b.x, b.y, b.z, b.w};
#pragma unroll
            for (int i = 0; i < 4; ++i)
#pragma unroll
                for (int j = 0; j < 4; ++j)
                    acc[i][j] = fmaf(ar[i], br[j], acc[i][j]);
        }
    }
#pragma unroll
    for (int i = 0; i < 4; ++i) {
        int row = tm + (ty << 2) + i;
        int col = tn + (tx << 2);
        float* cp = C + (long)row * ldc + col;
        float4 v;
        v.x = alpha * acc[i][0]; v.y = alpha * acc[i][1];
        v.z = alpha * acc[i][2]; v.w = alpha * acc[i][3];
        if (bias) {
            v.x += bias[col]; v.y += bias[col + 1];
            v.z += bias[col + 2]; v.w += bias[col + 3];
        }
        if (beta != 0.0f) {
            float4 o = *(const float4*)cp;
            v.x = fmaf(beta, o.x, v.x); v.y = fmaf(beta, o.y, v.y);
            v.z = fmaf(beta, o.z, v.z); v.w = fmaf(beta, o.w, v.w);
        }
        *(float4*)cp = v;
    }
}

// ---------- Gram: G'[b][t][s] = (LR/I)*(<x_t,x_s>+1), lower+diag 64x64 tiles only ----------
__global__ __launch_bounds__(256) void gram_kernel(const float* __restrict__ X,
                                                   float* __restrict__ G)
{
    const int tj = blockIdx.x, ti = blockIdx.y, b = blockIdx.z;
    if (tj > ti) return;
    const float* Xb = X + (long)b * SEQ * HD;
    __shared__ float As[16][64];
    __shared__ float Bsh[16][64];
    const int tid = threadIdx.x;
    const int tx = tid & 15, ty = tid >> 4;
    const int m = tid >> 2, k4 = (tid & 3) << 2;
    float acc[4][4] = {};
    for (int k0 = 0; k0 < HD; k0 += 16) {
        float4 av = *(const float4*)(Xb + (long)(ti * 64 + m) * HD + (k0 + k4));
        float4 bv = *(const float4*)(Xb + (long)(tj * 64 + m) * HD + (k0 + k4));
        __syncthreads();
        As[k4 + 0][m] = av.x; As[k4 + 1][m] = av.y; As[k4 + 2][m] = av.z; As[k4 + 3][m] = av.w;
        Bsh[k4 + 0][m] = bv.x; Bsh[k4 + 1][m] = bv.y; Bsh[k4 + 2][m] = bv.z; Bsh[k4 + 3][m] = bv.w;
        __syncthreads();
#pragma unroll
        for (int k = 0; k < 16; ++k) {
            float4 a = *(const float4*)&As[k][ty << 2];
            float4 b2 = *(const float4*)&Bsh[k][tx << 2];
            float ar[4] = {a.x, a.y, a.z, a.w};
            float br[4] = {b2.x, b2.y, b2.z, b2.w};
#pragma unroll
            for (int i = 0; i < 4; ++i)
#pragma unroll
                for (int j = 0; j < 4; ++j)
                    acc[i][j] = fmaf(ar[i], br[j], acc[i][j]);
        }
    }
    float* Gb = G + (long)b * SEQ * SEQ;
#pragma unroll
    for (int i = 0; i < 4; ++i) {
        int row = ti * 64 + (ty << 2) + i;
        int col = tj * 64 + (tx << 2);
        float4 v;
        v.x = LR_OVER_I * (acc[i][0] + 1.0f);
        v.y = LR_OVER_I * (acc[i][1] + 1.0f);
        v.z = LR_OVER_I * (acc[i][2] + 1.0f);
        v.w = LR_OVER_I * (acc[i][3] + 1.0f);
        *(float4*)(Gb + (long)row * SEQ + col) = v;
    }
}

// ---------- intra-chunk unit-lower-triangular solve (64 steps, unrolled) ----------
// err_t -= sum_{s<t} a[t][s]*err_s within the diagonal chunk. Coefficients are
// wave-uniform (block-indexed) -> scalar loads; column history in registers.
__global__ __launch_bounds__(256) void intra_solve(float* __restrict__ err,
                                                   const float* __restrict__ gram, int c)
{
    const int b = blockIdx.x >> 2;
    const int j = ((blockIdx.x & 3) << 8) + threadIdx.x;
    const int t0 = c << 6;
    float* E = err + (long)b * SEQ * ID + (long)t0 * ID + j;
    const float* Gp = gram + (long)b * SEQ * SEQ + (long)t0 * SEQ + t0;
    float e[64];
    e[0] = E[0];
#pragma unroll
    for (int t = 1; t < 64; ++t) {
        float v = E[(long)t * ID];
#pragma unroll
        for (int s = 0; s < t; ++s)
            v = fmaf(-Gp[t * SEQ + s], e[s], v);
        e[t] = v;
        E[(long)t * ID] = v;
    }
}

// ---------- h = silu(err + target), written over target ----------
__global__ void silu_kernel(const float* __restrict__ err, float* __restrict__ tgt)
{
    long i = ((long)blockIdx.x * 256 + threadIdx.x) * 4;
    float4 e = *(const float4*)(err + i);
    float4 t = *(const float4*)(tgt + i);
    float4 r;
    float v;
    v = e.x + t.x; r.x = v / (1.0f + __expf(-v));
    v = e.y + t.y; r.y = v / (1.0f + __expf(-v));
    v = e.z + t.z; r.z = v / (1.0f + __expf(-v));
    v = e.w + t.w; r.w = v / (1.0f + __expf(-v));
    *(float4*)(tgt + i) = r;
}

// ---------- gate + residual mix + LayerNorm ----------
__global__ __launch_bounds__(256) void gate_ln(
    const float* __restrict__ z, const float* __restrict__ ttt,
    const float* __restrict__ x, const float* __restrict__ gamma,
    const float* __restrict__ bet, float* __restrict__ out)
{
    long base = (long)blockIdx.x * HD + threadIdx.x * 4;
    float4 zv = *(const float4*)(z + base);
    float4 tv = *(const float4*)(ttt + base);
    float4 xv = *(const float4*)(x + base);
    float y[4];
    {
        float g;
        g = 1.0f / (1.0f + __expf(-zv.x)); y[0] = g * tv.x + (1.0f - g) * xv.x;
        g = 1.0f / (1.0f + __expf(-zv.y)); y[1] = g * tv.y + (1.0f - g) * xv.y;
        g = 1.0f / (1.0f + __expf(-zv.z)); y[2] = g * tv.z + (1.0f - g) * xv.z;
        g = 1.0f / (1.0f + __expf(-zv.w)); y[3] = g * tv.w + (1.0f - g) * xv.w;
    }
    float sum = y[0] + y[1] + y[2] + y[3];
    float sq  = y[0]*y[0] + y[1]*y[1] + y[2]*y[2] + y[3]*y[3];
#pragma unroll
    for (int off = 32; off > 0; off >>= 1) {
        sum += __shfl_down(sum, off);
        sq  += __shfl_down(sq, off);
    }
    __shared__ float s1[4], s2[4];
    int wid = threadIdx.x >> 6;
    if ((threadIdx.x & 63) == 0) { s1[wid] = sum; s2[wid] = sq; }
    __syncthreads();
    float tot = s1[0] + s1[1] + s1[2] + s1[3];
    float tsq = s2[0] + s2[1] + s2[2] + s2[3];
    float mu = tot * (1.0f / HD);
    float var = tsq * (1.0f / HD) - mu * mu;
    float rs = rsqrtf(var + 1e-5f);
    int col = threadIdx.x * 4;
    float4 ov;
    ov.x = (y[0] - mu) * rs * gamma[col + 0] + bet[col + 0];
    ov.y = (y[1] - mu) * rs * gamma[col + 1] + bet[col + 1];
    ov.z = (y[2] - mu) * rs * gamma[col + 2] + bet[col + 2];
    ov.w = (y[3] - mu) * rs * gamma[col + 3] + bet[col + 3];
    *(float4*)(out + base) = ov;
}

extern "C" void kernel_launch(void* const* d_in, const int* in_sizes, int n_in,
                              void* d_out, int out_size, void* d_ws, size_t ws_size,
                              hipStream_t stream)
{
    const float* x    = (const float*)d_in[0];
    const float* Wi   = (const float*)d_in[1];
    const float* bi   = (const float*)d_in[2];
    const float* Wt   = (const float*)d_in[3];
    const float* bt   = (const float*)d_in[4];
    const float* Wo   = (const float*)d_in[5];
    const float* bo   = (const float*)d_in[6];
    const float* Wg   = (const float*)d_in[7];
    const float* bg   = (const float*)d_in[8];
    const float* gam  = (const float*)d_in[9];
    const float* bet  = (const float*)d_in[10];
    float* out = (float*)d_out;

    float* u    = (float*)d_ws;                  // [BS, ID]  err / later gate-preact
    float* tgt  = u    + (long)BS * ID;          // [BS, ID]  target / later h=silu(inner)
    float* ttt  = tgt  + (long)BS * ID;          // [BS, HD]
    float* gram = ttt  + (long)BS * HD;          // [BATCH, SEQ, SEQ] scaled coeffs
    float* Wd   = gram + (long)BATCH * SEQ * SEQ;// [HD, ID]
    float* bd   = Wd   + (long)HD * ID;          // [ID]

    prep_kernel<<<4096, 256, 0, stream>>>(Wi, Wt, bi, bt, Wd, bd);

    dim3 gBig(ID / 64, BS / 64, 1);
    // u = X @ (W_init - Wt) + (b_init - bt)
    gemm_f32<<<gBig, 256, 0, stream>>>(x, 0, HD, Wd, 0, ID, u, 0, ID, HD, bd, 1.f, 0.f);
    // target = X @ Wt + bt
    gemm_f32<<<gBig, 256, 0, stream>>>(x, 0, HD, Wt, 0, ID, tgt, 0, ID, HD, bt, 1.f, 0.f);
    // scaled Gram coefficients
    gram_kernel<<<dim3(8, 8, BATCH), 256, 0, stream>>>(x, gram);

    // blocked forward substitution: err = (I + A_strict)^-1 u
    for (int c = 0; c < NCHUNK; ++c) {
        if (c > 0) {
            dim3 gX(ID / 64, 1, BATCH);
            gemm_f32<<<gX, 256, 0, stream>>>(
                gram + (long)c * CHUNK * SEQ, (long)SEQ * SEQ, SEQ,
                u, (long)SEQ * ID, ID,
                u + (long)c * CHUNK * ID, (long)SEQ * ID, ID,
                c * CHUNK, nullptr, -1.f, 1.f);
        }
        intra_solve<<<BATCH * 4, 256, 0, stream>>>(u, gram, c);
    }

    // h = silu(err + target) -> tgt
    silu_kernel<<<(BS * (long)ID / 4) / 256, 256, 0, stream>>>(u, tgt);
    // ttt = h @ Wo + bo
    gemm_f32<<<gBig, 256, 0, stream>>>(tgt, 0, ID, Wo, 0, HD, ttt, 0, HD, ID, bo, 1.f, 0.f);
    // z = x @ Wg_top + bg ; z += ttt @ Wg_bot   (into u)
    gemm_f32<<<gBig, 256, 0, stream>>>(x, 0, HD, Wg, 0, HD, u, 0, HD, HD, bg, 1.f, 0.f);
    gemm_f32<<<gBig, 256, 0, stream>>>(ttt, 0, HD, Wg + (long)HD * HD, 0, HD, u, 0, HD, HD,
                                       nullptr, 1.f, 1.f);
    // out = LN(g*ttt + (1-g)*x)
    gate_ln<<<BS, 256, 0, stream>>>(u, ttt, x, gam, bet, out);
}

// Round 3
// 1659.112 us; speedup vs baseline: 3.5713x; 3.5713x over previous
//
#include <hip/hip_runtime.h>

#define HD 1024
#define ID 1024
#define BATCH 64
#define SEQ 512
#define BS (BATCH*SEQ)     // 32768 rows
#define CHUNK 64
#define NCHUNK (SEQ/CHUNK) // 8
#define LR_OVER_I (0.01f/1024.0f)

typedef unsigned int u32;
typedef unsigned short ushort_t;
typedef __attribute__((ext_vector_type(8))) short short8;        // 8 bf16 (4 VGPRs)
typedef __attribute__((ext_vector_type(8))) unsigned short ushort8;
typedef __attribute__((ext_vector_type(4))) float floatx4;

__device__ inline ushort_t f2bf(float f) {
    union { float f; u32 u; } v; v.f = f;
    return (ushort_t)((v.u + 0x7FFFu + ((v.u >> 16) & 1u)) >> 16);  // RNE
}

__device__ inline void load_lds16(const void* g, void* l) {
    __builtin_amdgcn_global_load_lds(
        (const __attribute__((address_space(1))) u32*)g,
        (__attribute__((address_space(3))) u32*)l, 16, 0, 0);
}

// ---------- bd = b_init - bt ----------
__global__ void prep_b(const float* __restrict__ bi, const float* __restrict__ bt,
                       float* __restrict__ bd)
{
    int i = blockIdx.x * 256 + threadIdx.x;
    if (i < ID) bd[i] = bi[i] - bt[i];
}

// ---------- WdT = bf16((Wi - Wt)^T), WtT = bf16(Wt^T) ----------
__global__ void prep_w(const float* __restrict__ Wi, const float* __restrict__ Wt,
                       ushort_t* __restrict__ WdT, ushort_t* __restrict__ WtT)
{
    __shared__ float ti[32][33], tt[32][33];
    int r0 = blockIdx.y * 32, c0 = blockIdx.x * 32;
    for (int i = threadIdx.y; i < 32; i += 8) {
        ti[i][threadIdx.x] = Wi[(long)(r0 + i) * ID + c0 + threadIdx.x];
        tt[i][threadIdx.x] = Wt[(long)(r0 + i) * ID + c0 + threadIdx.x];
    }
    __syncthreads();
    for (int i = threadIdx.y; i < 32; i += 8) {
        float wi = ti[threadIdx.x][i];
        float wt = tt[threadIdx.x][i];
        WdT[(long)(c0 + i) * HD + r0 + threadIdx.x] = f2bf(wi - wt);
        WtT[(long)(c0 + i) * HD + r0 + threadIdx.x] = f2bf(wt);
    }
}

// ---------- out[C][R] = bf16(in[R][C]^T) ----------
__global__ void transpose_bf16(const float* __restrict__ in, ushort_t* __restrict__ out,
                               int R, int C)
{
    __shared__ float t[32][33];
    int r0 = blockIdx.y * 32, c0 = blockIdx.x * 32;
    for (int i = threadIdx.y; i < 32; i += 8)
        t[i][threadIdx.x] = in[(long)(r0 + i) * C + c0 + threadIdx.x];
    __syncthreads();
    for (int i = threadIdx.y; i < 32; i += 8)
        out[(long)(c0 + i) * R + r0 + threadIdx.x] = f2bf(t[threadIdx.x][i]);
}

// ---------- fp32 -> bf16 ----------
__global__ void convert_bf16(const float* __restrict__ in, ushort_t* __restrict__ out)
{
    long i = ((long)blockIdx.x * 256 + threadIdx.x) * 8;
    float4 a = *(const float4*)(in + i);
    float4 b = *(const float4*)(in + i + 4);
    ushort8 o;
    o[0] = f2bf(a.x); o[1] = f2bf(a.y); o[2] = f2bf(a.z); o[3] = f2bf(a.w);
    o[4] = f2bf(b.x); o[5] = f2bf(b.y); o[6] = f2bf(b.z); o[7] = f2bf(b.w);
    *(ushort8*)(out + i) = o;
}

// ---------- bf16 MFMA GEMM: C = alpha*(A @ Bt^T) + add0 + bias + beta*C ----------
// A [M,K] bf16 row-major, Bt [N,K] bf16 row-major, C fp32 [M,N].
// 128x128 tile, BK=32, 4 waves each 64x64 via 4x4 mfma_f32_16x16x32_bf16.
__global__ __launch_bounds__(256, 3) void gemm_bf16(
    const ushort_t* __restrict__ A, long sAb, int lda,
    const ushort_t* __restrict__ Bt, long sBb, int ldb,
    float* __restrict__ C, long sCb, int ldc,
    int K, const float* __restrict__ bias,
    float alpha, float add0, float beta)
{
    __shared__ ushort_t As[128 * 32];
    __shared__ ushort_t Bs[128 * 32];
    A  += (long)blockIdx.z * sAb;
    Bt += (long)blockIdx.z * sBb;
    C  += (long)blockIdx.z * sCb;
    const int M0 = blockIdx.y * 128, N0 = blockIdx.x * 128;
    const int tid = threadIdx.x;
    const int wave = tid >> 6, lane = tid & 63;
    const int lr = lane & 15, lq = lane >> 4;
    const int wm = (wave & 1) * 64, wn = (wave >> 1) * 64;

    // staging: lane l covers (row = l>>2, kq = l&3); LDS row-major [128][32] bf16,
    // so lane data lands at base + l*16B exactly (global_load_lds lane order).
    const ushort_t* ga0 = A  + (long)(M0 + wave * 16 + (lane >> 2)) * lda + (lane & 3) * 8;
    const ushort_t* ga1 = ga0 + 64L * lda;
    const ushort_t* gb0 = Bt + (long)(N0 + wave * 16 + (lane >> 2)) * ldb + (lane & 3) * 8;
    const ushort_t* gb1 = gb0 + 64L * ldb;
    ushort_t* la0 = &As[(wave * 16)      * 32];
    ushort_t* la1 = &As[(wave * 16 + 64) * 32];
    ushort_t* lb0 = &Bs[(wave * 16)      * 32];
    ushort_t* lb1 = &Bs[(wave * 16 + 64) * 32];

    floatx4 acc[4][4] = {};

    for (int k0 = 0; k0 < K; k0 += 32) {
        load_lds16(ga0, la0);
        load_lds16(ga1, la1);
        load_lds16(gb0, lb0);
        load_lds16(gb1, lb1);
        ga0 += 32; ga1 += 32; gb0 += 32; gb1 += 32;
        __syncthreads();   // compiler emits vmcnt(0) drain before s_barrier
        short8 af[4], bf4[4];
#pragma unroll
        for (int i = 0; i < 4; ++i)
            af[i] = *(const short8*)&As[(wm + i * 16 + lr) * 32 + lq * 8];
#pragma unroll
        for (int j = 0; j < 4; ++j)
            bf4[j] = *(const short8*)&Bs[(wn + j * 16 + lr) * 32 + lq * 8];
#pragma unroll
        for (int i = 0; i < 4; ++i)
#pragma unroll
            for (int j = 0; j < 4; ++j)
                acc[i][j] = __builtin_amdgcn_mfma_f32_16x16x32_bf16(
                    af[i], bf4[j], acc[i][j], 0, 0, 0);
        __syncthreads();
    }

    // C/D layout: col = lane&15, row = (lane>>4)*4 + reg
    float bv[4] = {0.f, 0.f, 0.f, 0.f};
    if (bias) {
#pragma unroll
        for (int j = 0; j < 4; ++j) bv[j] = bias[N0 + wn + j * 16 + lr];
    }
#pragma unroll
    for (int i = 0; i < 4; ++i) {
#pragma unroll
        for (int r = 0; r < 4; ++r) {
            int row = M0 + wm + i * 16 + lq * 4 + r;
            float* cp = C + (long)row * ldc + N0 + wn + lr;
#pragma unroll
            for (int j = 0; j < 4; ++j) {
                float v = alpha * acc[i][j][r] + add0 + bv[j];
                if (beta != 0.0f) v += beta * cp[j * 16];
                cp[j * 16] = v;
            }
        }
    }
}

// ---------- fp32 GEMM (inter-chunk solve): C = alpha*(A@B) + beta*C ----------
__global__ __launch_bounds__(256) void gemm_f32(
    const float* __restrict__ A, long sAb, int lda,
    const float* __restrict__ B, long sBb, int ldb,
    float* __restrict__ C, long sCb, int ldc,
    int K, const float* __restrict__ bias, float alpha, float beta)
{
    A += (long)blockIdx.z * sAb;
    B += (long)blockIdx.z * sBb;
    C += (long)blockIdx.z * sCb;
    const int tn = blockIdx.x * 64;
    const int tm = blockIdx.y * 64;
    __shared__ float As[16][64];
    __shared__ float Bsh[16][64];
    const int tid = threadIdx.x;
    const int tx = tid & 15, ty = tid >> 4;
    const int am = tid >> 2, ak4 = (tid & 3) << 2;
    const int bk = tid >> 4, bn4 = (tid & 15) << 2;
    float acc[4][4] = {};
    for (int k0 = 0; k0 < K; k0 += 16) {
        float4 av = *(const float4*)(A + (long)(tm + am) * lda + (k0 + ak4));
        float4 bv = *(const float4*)(B + (long)(k0 + bk) * ldb + (tn + bn4));
        __syncthreads();
        As[ak4 + 0][am] = av.x; As[ak4 + 1][am] = av.y;
        As[ak4 + 2][am] = av.z; As[ak4 + 3][am] = av.w;
        *(float4*)&Bsh[bk][bn4] = bv;
        __syncthreads();
#pragma unroll
        for (int k = 0; k < 16; ++k) {
            float4 a = *(const float4*)&As[k][ty << 2];
            float4 b = *(const float4*)&Bsh[k][tx << 2];
            float ar[4] = {a.x, a.y, a.z, a.w};
            float br[4] = {b.x, b.y, b.z, b.w};
#pragma unroll
            for (int i = 0; i < 4; ++i)
#pragma unroll
                for (int j = 0; j < 4; ++j)
                    acc[i][j] = fmaf(ar[i], br[j], acc[i][j]);
        }
    }
#pragma unroll
    for (int i = 0; i < 4; ++i) {
        int row = tm + (ty << 2) + i;
        int col = tn + (tx << 2);
        float* cp = C + (long)row * ldc + col;
        float4 v;
        v.x = alpha * acc[i][0]; v.y = alpha * acc[i][1];
        v.z = alpha * acc[i][2]; v.w = alpha * acc[i][3];
        if (bias) {
            v.x += bias[col]; v.y += bias[col + 1];
            v.z += bias[col + 2]; v.w += bias[col + 3];
        }
        if (beta != 0.0f) {
            float4 o = *(const float4*)cp;
            v.x = fmaf(beta, o.x, v.x); v.y = fmaf(beta, o.y, v.y);
            v.z = fmaf(beta, o.z, v.z); v.w = fmaf(beta, o.w, v.w);
        }
        *(float4*)cp = v;
    }
}

// ---------- intra-chunk unit-lower-triangular solve (64 steps, unrolled) ----------
__global__ __launch_bounds__(256) void intra_solve(float* __restrict__ err,
                                                   const float* __restrict__ gram, int c)
{
    const int b = blockIdx.x >> 2;
    const int j = ((blockIdx.x & 3) << 8) + threadIdx.x;
    const int t0 = c << 6;
    float* E = err + (long)b * SEQ * ID + (long)t0 * ID + j;
    const float* Gp = gram + (long)b * SEQ * SEQ + (long)t0 * SEQ + t0;
    float e[64];
    e[0] = E[0];
#pragma unroll
    for (int t = 1; t < 64; ++t) {
        float v = E[(long)t * ID];
#pragma unroll
        for (int s = 0; s < t; ++s)
            v = fmaf(-Gp[t * SEQ + s], e[s], v);
        e[t] = v;
        E[(long)t * ID] = v;
    }
}

// ---------- hb = bf16(silu(err + target)) ----------
__global__ void silu_kernel(const float* __restrict__ err, const float* __restrict__ tgt,
                            ushort_t* __restrict__ hb)
{
    long i = ((long)blockIdx.x * 256 + threadIdx.x) * 8;
    float4 e0 = *(const float4*)(err + i);
    float4 e1 = *(const float4*)(err + i + 4);
    float4 t0 = *(const float4*)(tgt + i);
    float4 t1 = *(const float4*)(tgt + i + 4);
    float in[8] = {e0.x + t0.x, e0.y + t0.y, e0.z + t0.z, e0.w + t0.w,
                   e1.x + t1.x, e1.y + t1.y, e1.z + t1.z, e1.w + t1.w};
    ushort8 o;
#pragma unroll
    for (int k = 0; k < 8; ++k) {
        float v = in[k];
        o[k] = f2bf(v / (1.0f + __expf(-v)));
    }
    *(ushort8*)(hb + i) = o;
}

// ---------- gate + residual mix + LayerNorm ----------
__global__ __launch_bounds__(256) void gate_ln(
    const float* __restrict__ z, const float* __restrict__ ttt,
    const float* __restrict__ x, const float* __restrict__ gamma,
    const float* __restrict__ bet, float* __restrict__ out)
{
    long base = (long)blockIdx.x * HD + threadIdx.x * 4;
    float4 zv = *(const float4*)(z + base);
    float4 tv = *(const float4*)(ttt + base);
    float4 xv = *(const float4*)(x + base);
    float y[4];
    {
        float g;
        g = 1.0f / (1.0f + __expf(-zv.x)); y[0] = g * tv.x + (1.0f - g) * xv.x;
        g = 1.0f / (1.0f + __expf(-zv.y)); y[1] = g * tv.y + (1.0f - g) * xv.y;
        g = 1.0f / (1.0f + __expf(-zv.z)); y[2] = g * tv.z + (1.0f - g) * xv.z;
        g = 1.0f / (1.0f + __expf(-zv.w)); y[3] = g * tv.w + (1.0f - g) * xv.w;
    }
    float sum = y[0] + y[1] + y[2] + y[3];
    float sq  = y[0]*y[0] + y[1]*y[1] + y[2]*y[2] + y[3]*y[3];
#pragma unroll
    for (int off = 32; off > 0; off >>= 1) {
        sum += __shfl_down(sum, off);
        sq  += __shfl_down(sq, off);
    }
    __shared__ float s1[4], s2[4];
    int wid = threadIdx.x >> 6;
    if ((threadIdx.x & 63) == 0) { s1[wid] = sum; s2[wid] = sq; }
    __syncthreads();
    float tot = s1[0] + s1[1] + s1[2] + s1[3];
    float tsq = s2[0] + s2[1] + s2[2] + s2[3];
    float mu = tot * (1.0f / HD);
    float var = tsq * (1.0f / HD) - mu * mu;
    float rs = rsqrtf(var + 1e-5f);
    int col = threadIdx.x * 4;
    float4 ov;
    ov.x = (y[0] - mu) * rs * gamma[col + 0] + bet[col + 0];
    ov.y = (y[1] - mu) * rs * gamma[col + 1] + bet[col + 1];
    ov.z = (y[2] - mu) * rs * gamma[col + 2] + bet[col + 2];
    ov.w = (y[3] - mu) * rs * gamma[col + 3] + bet[col + 3];
    *(float4*)(out + base) = ov;
}

extern "C" void kernel_launch(void* const* d_in, const int* in_sizes, int n_in,
                              void* d_out, int out_size, void* d_ws, size_t ws_size,
                              hipStream_t stream)
{
    const float* x    = (const float*)d_in[0];
    const float* Wi   = (const float*)d_in[1];
    const float* bi   = (const float*)d_in[2];
    const float* Wt   = (const float*)d_in[3];
    const float* bt   = (const float*)d_in[4];
    const float* Wo   = (const float*)d_in[5];
    const float* bo   = (const float*)d_in[6];
    const float* Wg   = (const float*)d_in[7];
    const float* bg   = (const float*)d_in[8];
    const float* gam  = (const float*)d_in[9];
    const float* bet  = (const float*)d_in[10];
    float* out = (float*)d_out;

    // Workspace plan (~394 MB; R1's 452 MB layout was in-bounds, R2's 522 MB faulted):
    //   u    [BS,ID] f32 128MB : err through solve, then z (gate preact)
    //   tgt  [BS,ID] f32 128MB : target; AFTER silu reused as ttt f32 [BS,HD]
    //   gram [B,S,S] f32  64MB : solve coeffs; AFTER solve reused as hb bf16 [BS,ID]
    //   xb   [BS,HD] bf16 64MB : x in bf16; AFTER z=x@Wg1 reused as tttb bf16
    //   weights bf16 ~10MB + bd
    float* u    = (float*)d_ws;
    float* tgt  = u    + (long)BS * ID;
    float* gram = tgt  + (long)BS * ID;
    ushort_t* xb  = (ushort_t*)(gram + (long)BATCH * SEQ * SEQ);
    ushort_t* WdT = xb  + (long)BS * HD;              // [ID,HD] bf16 (N,K)
    ushort_t* WtT = WdT + (long)HD * ID;
    ushort_t* WoT = WtT + (long)HD * ID;              // [HD,ID] bf16
    ushort_t* WgT1 = WoT + (long)HD * ID;             // [HD,HD] bf16
    ushort_t* WgT2 = WgT1 + (long)HD * HD;
    float* bd = (float*)(WgT2 + (long)HD * HD);       // [ID]
    float* ttt      = tgt;                            // overlay: after silu
    ushort_t* hb    = (ushort_t*)gram;                // overlay: after solve
    ushort_t* tttb  = xb;                             // overlay: after z = x@Wg1

    // ---- prep: bias diff, weight transposes+bf16, x->bf16 ----
    prep_b<<<4, 256, 0, stream>>>(bi, bt, bd);
    prep_w<<<dim3(32, 32), dim3(32, 8), 0, stream>>>(Wi, Wt, WdT, WtT);
    transpose_bf16<<<dim3(32, 32), dim3(32, 8), 0, stream>>>(Wo, WoT, ID, HD);
    transpose_bf16<<<dim3(32, 32), dim3(32, 8), 0, stream>>>(Wg, WgT1, HD, HD);
    transpose_bf16<<<dim3(32, 32), dim3(32, 8), 0, stream>>>(Wg + (long)HD * HD, WgT2, HD, HD);
    convert_bf16<<<16384, 256, 0, stream>>>(x, xb);

    dim3 gBig(ID / 128, BS / 128, 1);   // 8 x 256
    // u = x @ (Wi - Wt) + (bi - bt)
    gemm_bf16<<<gBig, 256, 0, stream>>>(xb, 0, HD, WdT, 0, HD, u, 0, ID, HD, bd, 1.f, 0.f, 0.f);
    // target = x @ Wt + bt
    gemm_bf16<<<gBig, 256, 0, stream>>>(xb, 0, HD, WtT, 0, HD, tgt, 0, ID, HD, bt, 1.f, 0.f, 0.f);
    // gram = (LR/I) * (X X^T + 1), batched (full square; solve reads lower only)
    gemm_bf16<<<dim3(SEQ / 128, SEQ / 128, BATCH), 256, 0, stream>>>(
        xb, (long)SEQ * HD, HD, xb, (long)SEQ * HD, HD,
        gram, (long)SEQ * SEQ, SEQ, HD, nullptr, LR_OVER_I, LR_OVER_I, 0.f);

    // ---- blocked forward substitution: err = (I + A_strict)^-1 u ----
    for (int c = 0; c < NCHUNK; ++c) {
        if (c > 0) {
            dim3 gX(ID / 64, 1, BATCH);
            gemm_f32<<<gX, 256, 0, stream>>>(
                gram + (long)c * CHUNK * SEQ, (long)SEQ * SEQ, SEQ,
                u, (long)SEQ * ID, ID,
                u + (long)c * CHUNK * ID, (long)SEQ * ID, ID,
                c * CHUNK, nullptr, -1.f, 1.f);
        }
        intra_solve<<<BATCH * 4, 256, 0, stream>>>(u, gram, c);
    }

    // hb = bf16(silu(err + target))   (hb overlays gram — gram dead after solve)
    silu_kernel<<<16384, 256, 0, stream>>>(u, tgt, hb);
    // ttt = h @ Wo + bo               (ttt overlays tgt — tgt dead after silu)
    gemm_bf16<<<gBig, 256, 0, stream>>>(hb, 0, ID, WoT, 0, ID, ttt, 0, HD, ID, bo, 1.f, 0.f, 0.f);
    // z = x @ Wg_top + bg  (into u; err dead after silu) — uses xb, then xb dies
    gemm_bf16<<<gBig, 256, 0, stream>>>(xb, 0, HD, WgT1, 0, HD, u, 0, HD, HD, bg, 1.f, 0.f, 0.f);
    // tttb = bf16(ttt)                (tttb overlays xb — xb dead after z=x@Wg1)
    convert_bf16<<<16384, 256, 0, stream>>>(ttt, tttb);
    // z += ttt @ Wg_bot
    gemm_bf16<<<gBig, 256, 0, stream>>>(tttb, 0, HD, WgT2, 0, HD, u, 0, HD, HD, nullptr, 1.f, 0.f, 1.f);
    // out = LN(g*ttt + (1-g)*x)
    gate_ln<<<BS, 256, 0, stream>>>(u, ttt, x, gam, bet, out);
}

// Round 4
// 1400.110 us; speedup vs baseline: 4.2319x; 1.1850x over previous
//
#include <hip/hip_runtime.h>

#define HD 1024
#define ID 1024
#define BATCH 64
#define SEQ 512
#define BS (BATCH*SEQ)     // 32768 rows
#define CHUNK 64
#define NCHUNK (SEQ/CHUNK) // 8
#define LR_OVER_I (0.01f/1024.0f)

typedef unsigned int u32;
typedef unsigned short ushort_t;
typedef __attribute__((ext_vector_type(8))) short short8;        // 8 bf16 (4 VGPRs)
typedef __attribute__((ext_vector_type(8))) unsigned short ushort8;
typedef __attribute__((ext_vector_type(4))) unsigned short ushort4v;
typedef __attribute__((ext_vector_type(4))) float floatx4;

__device__ inline ushort_t f2bf(float f) {
    union { float f; u32 u; } v; v.f = f;
    return (ushort_t)((v.u + 0x7FFFu + ((v.u >> 16) & 1u)) >> 16);  // RNE
}
__device__ inline float bf2f(ushort_t h) {
    union { u32 u; float f; } v; v.u = ((u32)h) << 16; return v.f;
}

__device__ inline void load_lds16(const void* g, void* l) {
    __builtin_amdgcn_global_load_lds(
        (const __attribute__((address_space(1))) u32*)g,
        (__attribute__((address_space(3))) u32*)l, 16, 0, 0);
}

// ---------- bd = b_init - bt ----------
__global__ void prep_b(const float* __restrict__ bi, const float* __restrict__ bt,
                       float* __restrict__ bd)
{
    int i = blockIdx.x * 256 + threadIdx.x;
    if (i < ID) bd[i] = bi[i] - bt[i];
}

// ---------- WdT = bf16((Wi - Wt)^T), WtT = bf16(Wt^T) ----------
__global__ void prep_w(const float* __restrict__ Wi, const float* __restrict__ Wt,
                       ushort_t* __restrict__ WdT, ushort_t* __restrict__ WtT)
{
    __shared__ float ti[32][33], tt[32][33];
    int r0 = blockIdx.y * 32, c0 = blockIdx.x * 32;
    for (int i = threadIdx.y; i < 32; i += 8) {
        ti[i][threadIdx.x] = Wi[(long)(r0 + i) * ID + c0 + threadIdx.x];
        tt[i][threadIdx.x] = Wt[(long)(r0 + i) * ID + c0 + threadIdx.x];
    }
    __syncthreads();
    for (int i = threadIdx.y; i < 32; i += 8) {
        float wi = ti[threadIdx.x][i];
        float wt = tt[threadIdx.x][i];
        WdT[(long)(c0 + i) * HD + r0 + threadIdx.x] = f2bf(wi - wt);
        WtT[(long)(c0 + i) * HD + r0 + threadIdx.x] = f2bf(wt);
    }
}

// ---------- out[c][r] (row stride ldo) = bf16(in[r][c]) ----------
__global__ void transpose_bf16(const float* __restrict__ in, ushort_t* __restrict__ out,
                               int C, int ldo)
{
    __shared__ float t[32][33];
    int r0 = blockIdx.y * 32, c0 = blockIdx.x * 32;
    for (int i = threadIdx.y; i < 32; i += 8)
        t[i][threadIdx.x] = in[(long)(r0 + i) * C + c0 + threadIdx.x];
    __syncthreads();
    for (int i = threadIdx.y; i < 32; i += 8)
        out[(long)(c0 + i) * ldo + r0 + threadIdx.x] = f2bf(t[threadIdx.x][i]);
}

// ---------- fp32 -> bf16 ----------
__global__ void convert_bf16(const float* __restrict__ in, ushort_t* __restrict__ out)
{
    long i = ((long)blockIdx.x * 256 + threadIdx.x) * 8;
    float4 a = *(const float4*)(in + i);
    float4 b = *(const float4*)(in + i + 4);
    ushort8 o;
    o[0] = f2bf(a.x); o[1] = f2bf(a.y); o[2] = f2bf(a.z); o[3] = f2bf(a.w);
    o[4] = f2bf(b.x); o[5] = f2bf(b.y); o[6] = f2bf(b.z); o[7] = f2bf(b.w);
    *(ushort8*)(out + i) = o;
}

// ---------- bf16 MFMA GEMM: C = alpha*(A @ Bt^T) + add0 + bias ----------
// A = [A0 | A1] two optional K-segments (each KSEG wide), bf16 row-major.
// Bt [N, Ktot] bf16 row-major. C fp32 or bf16 (flags&1). flags&2: skip tiles N0>M0.
// 128x128 tile, BK=32, 4 waves each 64x64 via 4x4 mfma_f32_16x16x32_bf16.
// XCD-swizzle: M-tile pinned to xcd = L&7 so each A-tile is fetched by ONE XCD.
__global__ __launch_bounds__(256, 3) void gemm_bf16(
    const ushort_t* __restrict__ A0, long sA0, int lda0,
    const ushort_t* __restrict__ A1, long sA1, int lda1,
    const ushort_t* __restrict__ Bt, long sBb, int ldb,
    void* __restrict__ Cv, long sCb, int ldc,
    int KSEG, const float* __restrict__ bias,
    float alpha, float add0, int flags)
{
    int bx, by;
    {
        int L = blockIdx.y * gridDim.x + blockIdx.x;
        if ((gridDim.y & 7) == 0) {
            int xcd = L & 7, g = L >> 3;
            bx = g % gridDim.x;
            by = (g / gridDim.x) * 8 + xcd;
        } else { bx = blockIdx.x; by = blockIdx.y; }
    }
    const int M0 = by * 128, N0 = bx * 128;
    if ((flags & 2) && N0 > M0) return;

    __shared__ ushort_t As[128 * 32];
    __shared__ ushort_t Bs[128 * 32];
    const int tid = threadIdx.x;
    const int wave = tid >> 6, lane = tid & 63;
    const int lr = lane & 15, lq = lane >> 4;
    const int wm = (wave & 1) * 64, wn = (wave >> 1) * 64;

    ushort_t* la0 = &As[(wave * 16)      * 32];
    ushort_t* la1 = &As[(wave * 16 + 64) * 32];
    ushort_t* lb0 = &Bs[(wave * 16)      * 32];
    ushort_t* lb1 = &Bs[(wave * 16 + 64) * 32];

    // B staging pointer runs over the FULL K (both segments contiguous in Bt)
    const ushort_t* gb0 = Bt + (long)blockIdx.z * sBb
                        + (long)(N0 + wave * 16 + (lane >> 2)) * ldb + (lane & 3) * 8;
    const ushort_t* gb1 = gb0 + 64L * ldb;

    floatx4 acc[4][4] = {};

    for (int seg = 0; seg < 2; ++seg) {
        const ushort_t* Ag = (seg == 0) ? A0 : A1;
        if (!Ag) break;
        const int lda = (seg == 0) ? lda0 : lda1;
        Ag += (long)blockIdx.z * ((seg == 0) ? sA0 : sA1);
        const ushort_t* ga0 = Ag + (long)(M0 + wave * 16 + (lane >> 2)) * lda + (lane & 3) * 8;
        const ushort_t* ga1 = ga0 + 64L * lda;

        for (int k0 = 0; k0 < KSEG; k0 += 32) {
            load_lds16(ga0, la0);
            load_lds16(ga1, la1);
            load_lds16(gb0, lb0);
            load_lds16(gb1, lb1);
            ga0 += 32; ga1 += 32; gb0 += 32; gb1 += 32;
            __syncthreads();
            short8 af[4], bf4[4];
#pragma unroll
            for (int i = 0; i < 4; ++i)
                af[i] = *(const short8*)&As[(wm + i * 16 + lr) * 32 + lq * 8];
#pragma unroll
            for (int j = 0; j < 4; ++j)
                bf4[j] = *(const short8*)&Bs[(wn + j * 16 + lr) * 32 + lq * 8];
#pragma unroll
            for (int i = 0; i < 4; ++i)
#pragma unroll
                for (int j = 0; j < 4; ++j)
                    acc[i][j] = __builtin_amdgcn_mfma_f32_16x16x32_bf16(
                        af[i], bf4[j], acc[i][j], 0, 0, 0);
            __syncthreads();
        }
    }

    // C/D layout: col = lane&15, row = (lane>>4)*4 + reg
    float bv[4] = {0.f, 0.f, 0.f, 0.f};
    if (bias) {
#pragma unroll
        for (int j = 0; j < 4; ++j) bv[j] = bias[N0 + wn + j * 16 + lr];
    }
    if (flags & 1) {
        ushort_t* C = (ushort_t*)Cv + (long)blockIdx.z * sCb;
#pragma unroll
        for (int i = 0; i < 4; ++i)
#pragma unroll
            for (int r = 0; r < 4; ++r) {
                int row = M0 + wm + i * 16 + lq * 4 + r;
                ushort_t* cp = C + (long)row * ldc + N0 + wn + lr;
#pragma unroll
                for (int j = 0; j < 4; ++j)
                    cp[j * 16] = f2bf(alpha * acc[i][j][r] + add0 + bv[j]);
            }
    } else {
        float* C = (float*)Cv + (long)blockIdx.z * sCb;
#pragma unroll
        for (int i = 0; i < 4; ++i)
#pragma unroll
            for (int r = 0; r < 4; ++r) {
                int row = M0 + wm + i * 16 + lq * 4 + r;
                float* cp = C + (long)row * ldc + N0 + wn + lr;
#pragma unroll
                for (int j = 0; j < 4; ++j)
                    cp[j * 16] = alpha * acc[i][j][r] + add0 + bv[j];
            }
    }
}

// ---------- fp32 GEMM (inter-chunk solve): C = alpha*(A@B) + beta*C ----------
__global__ __launch_bounds__(256) void gemm_f32(
    const float* __restrict__ A, long sAb, int lda,
    const float* __restrict__ B, long sBb, int ldb,
    float* __restrict__ C, long sCb, int ldc,
    int K, const float* __restrict__ bias, float alpha, float beta)
{
    A += (long)blockIdx.z * sAb;
    B += (long)blockIdx.z * sBb;
    C += (long)blockIdx.z * sCb;
    const int tn = blockIdx.x * 64;
    const int tm = blockIdx.y * 64;
    __shared__ float As[16][64];
    __shared__ float Bsh[16][64];
    const int tid = threadIdx.x;
    const int tx = tid & 15, ty = tid >> 4;
    const int am = tid >> 2, ak4 = (tid & 3) << 2;
    const int bk = tid >> 4, bn4 = (tid & 15) << 2;
    float acc[4][4] = {};
    for (int k0 = 0; k0 < K; k0 += 16) {
        float4 av = *(const float4*)(A + (long)(tm + am) * lda + (k0 + ak4));
        float4 bv = *(const float4*)(B + (long)(k0 + bk) * ldb + (tn + bn4));
        __syncthreads();
        As[ak4 + 0][am] = av.x; As[ak4 + 1][am] = av.y;
        As[ak4 + 2][am] = av.z; As[ak4 + 3][am] = av.w;
        *(float4*)&Bsh[bk][bn4] = bv;
        __syncthreads();
#pragma unroll
        for (int k = 0; k < 16; ++k) {
            float4 a = *(const float4*)&As[k][ty << 2];
            float4 b = *(const float4*)&Bsh[k][tx << 2];
            float ar[4] = {a.x, a.y, a.z, a.w};
            float br[4] = {b.x, b.y, b.z, b.w};
#pragma unroll
            for (int i = 0; i < 4; ++i)
#pragma unroll
                for (int j = 0; j < 4; ++j)
                    acc[i][j] = fmaf(ar[i], br[j], acc[i][j]);
        }
    }
#pragma unroll
    for (int i = 0; i < 4; ++i) {
        int row = tm + (ty << 2) + i;
        int col = tn + (tx << 2);
        float* cp = C + (long)row * ldc + col;
        float4 v;
        v.x = alpha * acc[i][0]; v.y = alpha * acc[i][1];
        v.z = alpha * acc[i][2]; v.w = alpha * acc[i][3];
        if (bias) {
            v.x += bias[col]; v.y += bias[col + 1];
            v.z += bias[col + 2]; v.w += bias[col + 3];
        }
        if (beta != 0.0f) {
            float4 o = *(const float4*)cp;
            v.x = fmaf(beta, o.x, v.x); v.y = fmaf(beta, o.y, v.y);
            v.z = fmaf(beta, o.z, v.z); v.w = fmaf(beta, o.w, v.w);
        }
        *(float4*)cp = v;
    }
}

// ---------- intra-chunk unit-lower-triangular solve (64 steps, unrolled) ----------
__global__ __launch_bounds__(256) void intra_solve(float* __restrict__ err,
                                                   const float* __restrict__ gram, int c)
{
    const int b = blockIdx.x >> 2;
    const int j = ((blockIdx.x & 3) << 8) + threadIdx.x;
    const int t0 = c << 6;
    float* E = err + (long)b * SEQ * ID + (long)t0 * ID + j;
    const float* Gp = gram + (long)b * SEQ * SEQ + (long)t0 * SEQ + t0;
    float e[64];
    e[0] = E[0];
#pragma unroll
    for (int t = 1; t < 64; ++t) {
        float v = E[(long)t * ID];
#pragma unroll
        for (int s = 0; s < t; ++s)
            v = fmaf(-Gp[t * SEQ + s], e[s], v);
        e[t] = v;
        E[(long)t * ID] = v;
    }
}

// ---------- hb = bf16(silu(err + target)), target in bf16 ----------
__global__ void silu_kernel(const float* __restrict__ err, const ushort_t* __restrict__ tgtb,
                            ushort_t* __restrict__ hb)
{
    long i = ((long)blockIdx.x * 256 + threadIdx.x) * 8;
    float4 e0 = *(const float4*)(err + i);
    float4 e1 = *(const float4*)(err + i + 4);
    ushort8 t8 = *(const ushort8*)(tgtb + i);
    float in[8] = {e0.x + bf2f(t8[0]), e0.y + bf2f(t8[1]),
                   e0.z + bf2f(t8[2]), e0.w + bf2f(t8[3]),
                   e1.x + bf2f(t8[4]), e1.y + bf2f(t8[5]),
                   e1.z + bf2f(t8[6]), e1.w + bf2f(t8[7])};
    ushort8 o;
#pragma unroll
    for (int k = 0; k < 8; ++k) {
        float v = in[k];
        o[k] = f2bf(v / (1.0f + __expf(-v)));
    }
    *(ushort8*)(hb + i) = o;
}

// ---------- gate + residual mix + LayerNorm (z, ttt in bf16) ----------
__global__ __launch_bounds__(256) void gate_ln(
    const ushort_t* __restrict__ zb, const ushort_t* __restrict__ tttb,
    const float* __restrict__ x, const float* __restrict__ gamma,
    const float* __restrict__ bet, float* __restrict__ out)
{
    long base = (long)blockIdx.x * HD + threadIdx.x * 4;
    ushort4v zv4 = *(const ushort4v*)(zb + base);
    ushort4v tv4 = *(const ushort4v*)(tttb + base);
    float4 xv = *(const float4*)(x + base);
    float xr[4] = {xv.x, xv.y, xv.z, xv.w};
    float y[4];
#pragma unroll
    for (int k = 0; k < 4; ++k) {
        float g = 1.0f / (1.0f + __expf(-bf2f(zv4[k])));
        float t = bf2f(tv4[k]);
        y[k] = g * t + (1.0f - g) * xr[k];
    }
    float sum = y[0] + y[1] + y[2] + y[3];
    float sq  = y[0]*y[0] + y[1]*y[1] + y[2]*y[2] + y[3]*y[3];
#pragma unroll
    for (int off = 32; off > 0; off >>= 1) {
        sum += __shfl_down(sum, off);
        sq  += __shfl_down(sq, off);
    }
    __shared__ float s1[4], s2[4];
    int wid = threadIdx.x >> 6;
    if ((threadIdx.x & 63) == 0) { s1[wid] = sum; s2[wid] = sq; }
    __syncthreads();
    float tot = s1[0] + s1[1] + s1[2] + s1[3];
    float tsq = s2[0] + s2[1] + s2[2] + s2[3];
    float mu = tot * (1.0f / HD);
    float var = tsq * (1.0f / HD) - mu * mu;
    float rs = rsqrtf(var + 1e-5f);
    int col = threadIdx.x * 4;
    float4 ov;
    ov.x = (y[0] - mu) * rs * gamma[col + 0] + bet[col + 0];
    ov.y = (y[1] - mu) * rs * gamma[col + 1] + bet[col + 1];
    ov.z = (y[2] - mu) * rs * gamma[col + 2] + bet[col + 2];
    ov.w = (y[3] - mu) * rs * gamma[col + 3] + bet[col + 3];
    *(float4*)(out + base) = ov;
}

extern "C" void kernel_launch(void* const* d_in, const int* in_sizes, int n_in,
                              void* d_out, int out_size, void* d_ws, size_t ws_size,
                              hipStream_t stream)
{
    const float* x    = (const float*)d_in[0];
    const float* Wi   = (const float*)d_in[1];
    const float* bi   = (const float*)d_in[2];
    const float* Wt   = (const float*)d_in[3];
    const float* bt   = (const float*)d_in[4];
    const float* Wo   = (const float*)d_in[5];
    const float* bo   = (const float*)d_in[6];
    const float* Wg   = (const float*)d_in[7];
    const float* bg   = (const float*)d_in[8];
    const float* gam  = (const float*)d_in[9];
    const float* bet  = (const float*)d_in[10];
    float* out = (float*)d_out;

    // Workspace ~394 MB (same footprint class as passing R3; R2's 522 MB faulted):
    //   u    [BS,ID] f32 128MB : RHS/err through solve; AFTER silu reused as zb bf16
    //   tgtb [BS,ID] bf16 64MB : target (bf16)
    //   gram [B,S,S] f32  64MB : solve coeffs; AFTER solve reused as hb bf16
    //   xb   [BS,HD] bf16 64MB : x bf16 (live until z GEMM)
    //   tttb [BS,HD] bf16 64MB : ttt (bf16, live through gate_ln)
    //   weights bf16 ~10MB + bd
    float* u       = (float*)d_ws;
    ushort_t* tgtb = (ushort_t*)(u + (long)BS * ID);
    float* gram    = (float*)(tgtb + (long)BS * ID);
    ushort_t* xb   = (ushort_t*)(gram + (long)BATCH * SEQ * SEQ);
    ushort_t* tttb = xb + (long)BS * HD;
    ushort_t* WdT  = tttb + (long)BS * HD;            // [ID,HD]
    ushort_t* WtT  = WdT + (long)HD * ID;             // [ID,HD]
    ushort_t* WoT  = WtT + (long)HD * ID;             // [HD,ID]
    ushort_t* WgT  = WoT + (long)HD * ID;             // [HD, 2*HD] concat K
    float* bd      = (float*)(WgT + (long)HD * 2 * HD);
    ushort_t* hb   = (ushort_t*)gram;                 // overlay: after solve
    ushort_t* zb   = (ushort_t*)u;                    // overlay: after silu

    // ---- prep ----
    prep_b<<<4, 256, 0, stream>>>(bi, bt, bd);
    prep_w<<<dim3(32, 32), dim3(32, 8), 0, stream>>>(Wi, Wt, WdT, WtT);
    transpose_bf16<<<dim3(32, 32), dim3(32, 8), 0, stream>>>(Wo, WoT, HD, ID);
    transpose_bf16<<<dim3(32, 32), dim3(32, 8), 0, stream>>>(Wg, WgT, HD, 2 * HD);
    transpose_bf16<<<dim3(32, 32), dim3(32, 8), 0, stream>>>(Wg + (long)HD * HD, WgT + HD, HD, 2 * HD);
    convert_bf16<<<16384, 256, 0, stream>>>(x, xb);

    dim3 gBig(ID / 128, BS / 128, 1);   // 8 x 256
    // u = x @ (Wi - Wt) + (bi - bt)   [f32 out]
    gemm_bf16<<<gBig, 256, 0, stream>>>(xb, 0, HD, nullptr, 0, 0, WdT, 0, HD,
                                        u, 0, ID, HD, bd, 1.f, 0.f, 0);
    // target = x @ Wt + bt            [bf16 out]
    gemm_bf16<<<gBig, 256, 0, stream>>>(xb, 0, HD, nullptr, 0, 0, WtT, 0, HD,
                                        tgtb, 0, ID, HD, bt, 1.f, 0.f, 1);
    // gram = (LR/I) * (X X^T + 1)     [f32 out, lower tiles only]
    gemm_bf16<<<dim3(SEQ / 128, SEQ / 128, BATCH), 256, 0, stream>>>(
        xb, (long)SEQ * HD, HD, nullptr, 0, 0, xb, (long)SEQ * HD, HD,
        gram, (long)SEQ * SEQ, SEQ, HD, nullptr, LR_OVER_I, LR_OVER_I, 2);

    // ---- blocked forward substitution: err = (I + A_strict)^-1 u ----
    for (int c = 0; c < NCHUNK; ++c) {
        if (c > 0) {
            dim3 gX(ID / 64, 1, BATCH);
            gemm_f32<<<gX, 256, 0, stream>>>(
                gram + (long)c * CHUNK * SEQ, (long)SEQ * SEQ, SEQ,
                u, (long)SEQ * ID, ID,
                u + (long)c * CHUNK * ID, (long)SEQ * ID, ID,
                c * CHUNK, nullptr, -1.f, 1.f);
        }
        intra_solve<<<BATCH * 4, 256, 0, stream>>>(u, gram, c);
    }

    // hb = bf16(silu(err + target))   (hb overlays gram)
    silu_kernel<<<16384, 256, 0, stream>>>(u, tgtb, hb);
    // ttt = h @ Wo + bo               [bf16 out]
    gemm_bf16<<<gBig, 256, 0, stream>>>(hb, 0, ID, nullptr, 0, 0, WoT, 0, ID,
                                        tttb, 0, HD, ID, bo, 1.f, 0.f, 1);
    // z = [x, ttt] @ Wg + bg          [bf16 out, two K-segments; zb overlays u]
    gemm_bf16<<<gBig, 256, 0, stream>>>(xb, 0, HD, tttb, 0, HD, WgT, 0, 2 * HD,
                                        zb, 0, HD, HD, bg, 1.f, 0.f, 1);
    // out = LN(g*ttt + (1-g)*x)
    gate_ln<<<BS, 256, 0, stream>>>(zb, tttb, x, gam, bet, out);
}